// Round 13
// baseline (121.972 us; speedup 1.0000x reference)
//
#include <hip/hip_runtime.h>
#include <hip/hip_bf16.h>

#define IN_FEAT 256
#define OUT_FEAT 32

#define RBC 128          // rows per bucket
#define NC_MAX 1024      // max buckets (n_nodes <= 131072)
#define CAPC 2560        // capacity per bucket: lambda=2046 (+11 sigma)
#define L1C 2048         // edges per part1 block (8 per thread, 256 threads)
#define OCAP 16384       // overflow list capacity
#define CNT_STRIDE 16    // u32 stride between counters (64B apart)
#define OBLK 64          // oflow blocks appended to row_spmm grid

typedef __attribute__((ext_vector_type(8))) short short8;
typedef __attribute__((ext_vector_type(4))) float f32x4;

__device__ __forceinline__ unsigned cvt_pk_bf16(float lo, float hi) {
    unsigned r;
    asm volatile("v_cvt_pk_bf16_f32 %0, %1, %2" : "=v"(r) : "v"(lo), "v"(hi));
    return r;
}
__device__ __forceinline__ float bf16lo(unsigned w) { return __uint_as_float(w << 16); }
__device__ __forceinline__ float bf16hi(unsigned w) { return __uint_as_float(w & 0xFFFF0000u); }
__device__ __forceinline__ float bf16s(unsigned short u) { return __uint_as_float(((unsigned)u) << 16); }

// ---------------------------------------------------------------------------
// Kernel 0: zero bucket counters + overflow counter.
// ---------------------------------------------------------------------------
__global__ __launch_bounds__(256) void zero_cnt_kernel(
    unsigned* __restrict__ p, int n_u32)
{
    const int i = blockIdx.x * 256 + threadIdx.x;
    if (i < n_u32) p[i] = 0u;
}

// ---------------------------------------------------------------------------
// Kernel 1: FUSED  [gemm: x16 = bf16(feat @ W)]  ||  [part1: bucket edges].
//   The two phases are data-independent; block-range split runs them
//   concurrently in one launch (serial 27+20us -> ~30us; combined HBM
//   demand ~134MB = ~4.8 TB/s < 6.3 achievable).
//   LDS: union of gemm's W^T stage (16.5 KB) and part1's sort area (36 KB).
// ---------------------------------------------------------------------------
__global__ __launch_bounds__(256) void fused_gemm_part1_kernel(
    const float* __restrict__ feat,
    const float* __restrict__ W,
    unsigned short* __restrict__ x16,
    int n_nodes, int ngemm,
    const float* __restrict__ vals,
    const int* __restrict__ erow,
    const int* __restrict__ ecol,
    uint2* __restrict__ buf1,
    unsigned* __restrict__ cnt1,
    unsigned* __restrict__ ocnt,
    uint4* __restrict__ obuf,
    int n_edges, int nc)
{
    __shared__ union {
        struct { short sWT[OUT_FEAT][IN_FEAT + 8]; } g;                  // 16.5 KB
        struct { uint2 sE[L1C]; unsigned short sBkt[L1C];
                 unsigned sHist[NC_MAX], sBase[NC_MAX],
                          sCur[NC_MAX], sGBase[NC_MAX]; } p;             // 36 KB
    } sm;

    const int tid = threadIdx.x;

    if ((int)blockIdx.x < ngemm) {
        // ================= GEMM path (proven 27us structure) ==============
        for (int i = tid; i < IN_FEAT * OUT_FEAT; i += 256) {
            const int k = i >> 5, c = i & 31;
            __hip_bfloat16 h = __float2bfloat16(W[i]);
            sm.g.sWT[c][k] = *reinterpret_cast<short*>(&h);
        }
        __syncthreads();

        const int wid  = tid >> 6;
        const int lane = tid & 63;
        const int tile = blockIdx.x * 4 + wid;
        const int row0 = tile * 16;
        if (row0 >= n_nodes) return;

        const int l16 = lane & 15;
        const int lh  = lane >> 4;

        if (row0 + 16 <= n_nodes) {
            const int row = row0 + l16;
            const float4* fr = reinterpret_cast<const float4*>(feat) + (size_t)row * (IN_FEAT / 4);

            float4 ra[8][2];
            #pragma unroll
            for (int ks = 0; ks < 8; ++ks) {
                ra[ks][0] = fr[ks * 8 + lh * 2];
                ra[ks][1] = fr[ks * 8 + lh * 2 + 1];
            }

            f32x4 acc0 = {0.f, 0.f, 0.f, 0.f};
            f32x4 acc1 = {0.f, 0.f, 0.f, 0.f};

            #pragma unroll
            for (int ks = 0; ks < 8; ++ks) {
                union { short8 s; unsigned u[4]; } af;
                af.u[0] = cvt_pk_bf16(ra[ks][0].x, ra[ks][0].y);
                af.u[1] = cvt_pk_bf16(ra[ks][0].z, ra[ks][0].w);
                af.u[2] = cvt_pk_bf16(ra[ks][1].x, ra[ks][1].y);
                af.u[3] = cvt_pk_bf16(ra[ks][1].z, ra[ks][1].w);

                const int k0 = ks * 32 + lh * 8;
                short8 b0 = *reinterpret_cast<const short8*>(&sm.g.sWT[l16][k0]);
                short8 b1 = *reinterpret_cast<const short8*>(&sm.g.sWT[16 + l16][k0]);

                acc0 = __builtin_amdgcn_mfma_f32_16x16x32_bf16(af.s, b0, acc0, 0, 0, 0);
                acc1 = __builtin_amdgcn_mfma_f32_16x16x32_bf16(af.s, b1, acc1, 0, 0, 0);
            }

            #pragma unroll
            for (int r = 0; r < 4; ++r) {
                const size_t orow = (size_t)(row0 + lh * 4 + r) * OUT_FEAT;
                const unsigned pk = cvt_pk_bf16(acc0[r], acc1[r]);
                x16[orow + l16]      = (unsigned short)(pk & 0xFFFFu);
                x16[orow + 16 + l16] = (unsigned short)(pk >> 16);
            }
        } else {
            const int rows = n_nodes - row0;
            for (int idx = lane; idx < rows * OUT_FEAT; idx += 64) {
                const int r = idx >> 5, j = idx & 31;
                float a = 0.f;
                for (int k = 0; k < IN_FEAT; ++k) {
                    unsigned wb = ((unsigned)(unsigned short)sm.g.sWT[j][k]) << 16;
                    a += feat[(size_t)(row0 + r) * IN_FEAT + k] * __uint_as_float(wb);
                }
                x16[(size_t)(row0 + r) * OUT_FEAT + j] =
                    (unsigned short)(cvt_pk_bf16(a, 0.f) & 0xFFFFu);
            }
        }
        return;
    }

    // ================= PART1 path (proven structure @256 thr) =============
    const int bid = (int)blockIdx.x - ngemm;
    const int chunk0 = bid * L1C;
    const int nq = n_edges >> 2;

    for (int b = tid; b < nc; b += 256) { sm.p.sHist[b] = 0; sm.p.sCur[b] = 0; }
    __syncthreads();

    int4 r4[2]; int4 c4[2]; float4 v4[2];
    #pragma unroll
    for (int i = 0; i < 2; ++i) {
        const int qi = (chunk0 >> 2) + tid + i * 256;
        if (qi < nq) {
            r4[i] = reinterpret_cast<const int4*>(erow)[qi];
            c4[i] = reinterpret_cast<const int4*>(ecol)[qi];
            v4[i] = reinterpret_cast<const float4*>(vals)[qi];
        } else {
            r4[i] = make_int4(-1, -1, -1, -1);
            c4[i] = make_int4(0, 0, 0, 0);
            v4[i] = make_float4(0.f, 0.f, 0.f, 0.f);
        }
    }

    #pragma unroll
    for (int i = 0; i < 2; ++i) {
        const int* rr = &r4[i].x;
        #pragma unroll
        for (int t = 0; t < 4; ++t)
            if (rr[t] >= 0) atomicAdd(&sm.p.sHist[rr[t] >> 7], 1u);
    }
    __syncthreads();

    if (tid == 0) {
        unsigned s = 0;
        for (int b = 0; b < nc; ++b) { sm.p.sBase[b] = s; s += sm.p.sHist[b]; }
    }
    __syncthreads();

    for (int b = tid; b < nc; b += 256)
        sm.p.sGBase[b] = sm.p.sHist[b]
            ? atomicAdd(&cnt1[(size_t)b * CNT_STRIDE], sm.p.sHist[b]) : 0u;
    __syncthreads();

    #pragma unroll
    for (int i = 0; i < 2; ++i) {
        const int*   rr = &r4[i].x;
        const int*   cc = &c4[i].x;
        const float* vv = &v4[i].x;
        #pragma unroll
        for (int t = 0; t < 4; ++t) {
            const int r = rr[t];
            if (r >= 0) {
                const int cb = r >> 7;
                unsigned p = sm.p.sBase[cb] + atomicAdd(&sm.p.sCur[cb], 1u);
                sm.p.sE[p] = make_uint2(((unsigned)(r & 127) << 17) | (unsigned)cc[t],
                                        __float_as_uint(vv[t]));
                sm.p.sBkt[p] = (unsigned short)cb;
            }
        }
    }
    __syncthreads();

    int total = n_edges - chunk0;
    if (total > L1C) total = L1C;
    for (int p = tid; p < total; p += 256) {
        const int cb = sm.p.sBkt[p];
        const unsigned g = sm.p.sGBase[cb] + (p - sm.p.sBase[cb]);
        const uint2 e = sm.p.sE[p];
        if (g < CAPC) {
            buf1[(size_t)cb * CAPC + g] = e;
        } else {
            unsigned o = atomicAdd(ocnt, 1u);
            if (o < OCAP)
                obuf[o] = make_uint4(((unsigned)cb << 7) | (e.x >> 17),
                                     e.x & 0x1FFFFu, e.y, 0u);
        }
    }

    if (bid == 0 && tid < (n_edges & 3)) {
        const int e = (nq << 2) + tid;
        unsigned o = atomicAdd(ocnt, 1u);
        if (o < OCAP)
            obuf[o] = make_uint4((unsigned)erow[e], (unsigned)ecol[e],
                                 __float_as_uint(vals[e]), 0u);
    }
}

// ---------------------------------------------------------------------------
// Kernel 2: in-place counting sort of each bucket by local row + CSR emit.
// ---------------------------------------------------------------------------
__global__ __launch_bounds__(512) void sort_kernel(
    uint2* __restrict__ buf1,
    const unsigned* __restrict__ cnt1,
    unsigned* __restrict__ rstart,
    unsigned* __restrict__ rcnt)
{
    __shared__ uint2 sorted[CAPC];                       // 20 KB
    __shared__ unsigned h[RBC], base[RBC], cur[RBC];

    const int tid = threadIdx.x;
    const int b = blockIdx.x;
    unsigned n = cnt1[(size_t)b * CNT_STRIDE];
    if (n > CAPC) n = CAPC;
    uint2* eb = buf1 + (size_t)b * CAPC;

    if (tid < RBC) { h[tid] = 0; cur[tid] = 0; }
    __syncthreads();

    uint2 e[5];   // 5*512 = 2560 = CAPC
    #pragma unroll
    for (int i = 0; i < 5; ++i) {
        const int p = tid + i * 512;
        e[i] = (p < (int)n) ? eb[p] : make_uint2(0xFFFFFFFFu, 0u);
    }
    #pragma unroll
    for (int i = 0; i < 5; ++i)
        if (e[i].x != 0xFFFFFFFFu) atomicAdd(&h[(e[i].x >> 17) & 127u], 1u);
    __syncthreads();

    if (tid == 0) {
        unsigned s = 0;
        for (int r = 0; r < RBC; ++r) { base[r] = s; s += h[r]; }
    }
    __syncthreads();

    #pragma unroll
    for (int i = 0; i < 5; ++i) {
        if (e[i].x != 0xFFFFFFFFu) {
            const unsigned r = (e[i].x >> 17) & 127u;
            const unsigned p = base[r] + atomicAdd(&cur[r], 1u);
            sorted[p] = e[i];
        }
    }
    __syncthreads();

    for (int i = tid; i < (int)n; i += 512) eb[i] = sorted[i];

    if (tid < RBC) {
        rstart[b * RBC + tid] = (unsigned)(b * CAPC) + base[tid];
        rcnt[b * RBC + tid]   = h[tid];
    }
}

// ---------------------------------------------------------------------------
// Kernel 3: CSR row-gather SpMM (bf16 x, zero atomics, zero LDS) with the
//   oflow cleanup folded in as OBLK trailing blocks (saves a launch).
// ---------------------------------------------------------------------------
__global__ __launch_bounds__(256) void row_spmm_kernel(
    const uint2* __restrict__ buf1,
    const unsigned* __restrict__ rstart,
    const unsigned* __restrict__ rcnt,
    const unsigned* __restrict__ xw,   // x bf16, read as uints (16/row)
    float* __restrict__ out,
    int n_nodes, int nrow_blocks,
    const uint4* __restrict__ obuf,
    const unsigned* __restrict__ ocnt)
{
    if ((int)blockIdx.x >= nrow_blocks) {
        // ---- overflow cleanup (expected zero work) ----
        unsigned n = *ocnt;
        if (n > OCAP) n = OCAP;
        const long long total = (long long)n * OUT_FEAT;
        const long long stride = (long long)OBLK * 256;
        for (long long idx = ((long long)blockIdx.x - nrow_blocks) * 256 + threadIdx.x;
             idx < total; idx += stride) {
            const int e = (int)(idx >> 5), j = (int)(idx & 31);
            uint4 p = obuf[e];
            const unsigned short* x16 = (const unsigned short*)xw;
            atomicAdd(&out[(size_t)p.x * OUT_FEAT + j],
                      __uint_as_float(p.z) * bf16s(x16[(size_t)p.y * OUT_FEAT + j]));
        }
        return;
    }

    const int wid  = threadIdx.x >> 6;
    const int lane = threadIdx.x & 63;
    const int row  = blockIdx.x * 4 + wid;
    if (row >= n_nodes) return;

    const unsigned s  = rstart[row];
    const unsigned cn = rcnt[row];
    const int slot = lane >> 4;      // 0..3
    const int jp   = lane & 15;      // feature pair

    float aLo = 0.f, aHi = 0.f;
    unsigned e = (unsigned)slot;
    for (; e + 4 < cn; e += 8) {
        const uint2 pa = buf1[s + e];
        const uint2 pb = buf1[s + e + 4];
        const unsigned wa = xw[(size_t)(pa.x & 0x1FFFFu) * 16 + jp];
        const unsigned wb = xw[(size_t)(pb.x & 0x1FFFFu) * 16 + jp];
        const float va = __uint_as_float(pa.y);
        const float vb = __uint_as_float(pb.y);
        aLo += va * bf16lo(wa) + vb * bf16lo(wb);
        aHi += va * bf16hi(wa) + vb * bf16hi(wb);
    }
    for (; e < cn; e += 4) {
        const uint2 p = buf1[s + e];
        const unsigned w = xw[(size_t)(p.x & 0x1FFFFu) * 16 + jp];
        const float v = __uint_as_float(p.y);
        aLo += v * bf16lo(w);
        aHi += v * bf16hi(w);
    }

    aLo += __shfl_down(aLo, 32, 64);
    aHi += __shfl_down(aHi, 32, 64);
    aLo += __shfl_down(aLo, 16, 64);
    aHi += __shfl_down(aHi, 16, 64);

    if (slot == 0) {
        float2 v = make_float2(aLo, aHi);
        *reinterpret_cast<float2*>(&out[(size_t)row * OUT_FEAT + 2 * jp]) = v;
    }
}

// ---------------------------------------------------------------------------
// Fallback: flat atomic scatter (needs fp32 x in ws) if ws/shape gate fails.
// ---------------------------------------------------------------------------
__global__ __launch_bounds__(256) void gemm_f32_fallback_kernel(
    const float* __restrict__ feat, const float* __restrict__ W,
    float* __restrict__ x, int n)
{
    // simple per-thread dot products (correctness-only path)
    const long long idx = (long long)blockIdx.x * 256 + threadIdx.x;
    if (idx >= (long long)n * OUT_FEAT) return;
    const int r = (int)(idx >> 5), j = (int)(idx & 31);
    float a = 0.f;
    for (int k = 0; k < IN_FEAT; ++k)
        a += feat[(size_t)r * IN_FEAT + k] * W[k * OUT_FEAT + j];
    x[idx] = a;
}

__global__ __launch_bounds__(256) void spmm_scatter_kernel(
    const float* __restrict__ vals,
    const int* __restrict__ erow,
    const int* __restrict__ ecol,
    const float* __restrict__ x,
    float* __restrict__ out,
    int n_edges)
{
    const long long idx = (long long)blockIdx.x * blockDim.x + threadIdx.x;
    const int e = (int)(idx >> 5);
    const int j = (int)(idx & 31);
    if (e >= n_edges) return;
    const float m = vals[e] * x[(size_t)ecol[e] * OUT_FEAT + j];
    atomicAdd(&out[(size_t)erow[e] * OUT_FEAT + j], m);
}

// ---------------------------------------------------------------------------
extern "C" void kernel_launch(void* const* d_in, const int* in_sizes, int n_in,
                              void* d_out, int out_size, void* d_ws, size_t ws_size,
                              hipStream_t stream)
{
    const float* feat = (const float*)d_in[0];
    const float* W    = (const float*)d_in[1];
    const float* vals = (const float*)d_in[2];
    const int*   erow = (const int*)d_in[3];
    const int*   ecol = (const int*)d_in[4];
    float* out = (float*)d_out;

    const int n_nodes = in_sizes[0] / IN_FEAT;
    const int n_edges = in_sizes[2];
    const int nc = (n_nodes + RBC - 1) / RBC;     // 782 buckets

    char* ws = (char*)d_ws;
    size_t off = 0;
    auto alloc = [&](size_t bytes) { size_t o = off; off = (off + bytes + 15) & ~(size_t)15; return o; };
    unsigned short* x16 = (unsigned short*)(ws + alloc((size_t)n_nodes * OUT_FEAT * sizeof(unsigned short)));
    uint2*    buf1   = (uint2*)(ws + alloc((size_t)nc * CAPC * sizeof(uint2)));
    unsigned* cnt1   = (unsigned*)(ws + alloc((size_t)nc * CNT_STRIDE * sizeof(unsigned)));
    unsigned* ocnt   = (unsigned*)(ws + alloc(sizeof(unsigned)));
    unsigned* rstart = (unsigned*)(ws + alloc((size_t)nc * RBC * sizeof(unsigned)));
    unsigned* rcnt   = (unsigned*)(ws + alloc((size_t)nc * RBC * sizeof(unsigned)));
    uint4*    obuf   = (uint4*)(ws + alloc((size_t)OCAP * sizeof(uint4)));

    const double lam = (nc > 0) ? (double)n_edges / nc : 0.0;
    const bool sorted_path = (ws_size >= off) && (nc <= NC_MAX) &&
                             (lam + 8.0 * sqrt(lam + 1.0) <= (double)CAPC);

    if (sorted_path) {
        // zero cnt1 + ocnt (ocnt sits immediately after cnt1, 16B-aligned)
        const int zn = nc * CNT_STRIDE + 4;
        zero_cnt_kernel<<<(zn + 255) / 256, 256, 0, stream>>>(cnt1, zn);

        // FUSED gemm || part1
        const int tiles = (n_nodes + 15) / 16;
        const int ngemm = (tiles + 3) / 4;
        const int npart = (n_edges + L1C - 1) / L1C;
        fused_gemm_part1_kernel<<<ngemm + npart, 256, 0, stream>>>(
            feat, W, x16, n_nodes, ngemm,
            vals, erow, ecol, buf1, cnt1, ocnt, obuf, n_edges, nc);

        sort_kernel<<<nc, 512, 0, stream>>>(buf1, cnt1, rstart, rcnt);

        const int nrow_blocks = (n_nodes + 3) / 4;
        row_spmm_kernel<<<nrow_blocks + OBLK, 256, 0, stream>>>(
            buf1, rstart, rcnt, (const unsigned*)x16, out, n_nodes,
            nrow_blocks, obuf, ocnt);
    } else {
        // fallback: fp32 x + flat atomic scatter (needs 12.8 MB ws only)
        float* xf = (float*)d_ws;
        hipMemsetAsync(d_out, 0, (size_t)out_size * sizeof(float), stream);
        long long xtot = (long long)n_nodes * OUT_FEAT;
        gemm_f32_fallback_kernel<<<(unsigned)((xtot + 255) / 256), 256, 0, stream>>>(
            feat, W, xf, n_nodes);
        long long total = (long long)n_edges * OUT_FEAT;
        spmm_scatter_kernel<<<(unsigned)((total + 255) / 256), 256, 0, stream>>>(
            vals, erow, ecol, xf, out, n_edges);
    }
}

// Round 14
// 108.885 us; speedup vs baseline: 1.1202x; 1.1202x over previous
//
#include <hip/hip_runtime.h>
#include <hip/hip_bf16.h>

#define IN_FEAT 256
#define OUT_FEAT 32

#define RBC 128          // rows per bucket
#define NC_MAX 1024      // max buckets (n_nodes <= 131072)
#define CAPC 2560        // capacity per bucket: lambda=2046 (+11 sigma)
#define L1_CHUNK 4096    // edges per part1 block (8/thread, 512 threads)
#define OCAP 16384       // overflow list capacity
#define CNT_STRIDE 16    // u32 stride between counters (64B apart)
#define OBLK 64          // oflow blocks appended to row_spmm grid

typedef __attribute__((ext_vector_type(8))) short short8;
typedef __attribute__((ext_vector_type(4))) float f32x4;

__device__ __forceinline__ unsigned cvt_pk_bf16(float lo, float hi) {
    unsigned r;
    asm volatile("v_cvt_pk_bf16_f32 %0, %1, %2" : "=v"(r) : "v"(lo), "v"(hi));
    return r;
}
__device__ __forceinline__ float bf16lo(unsigned w) { return __uint_as_float(w << 16); }
__device__ __forceinline__ float bf16hi(unsigned w) { return __uint_as_float(w & 0xFFFF0000u); }
__device__ __forceinline__ float bf16s(unsigned short u) { return __uint_as_float(((unsigned)u) << 16); }

// ---------------------------------------------------------------------------
// Kernel 0: zero bucket counters + overflow counter.
// ---------------------------------------------------------------------------
__global__ __launch_bounds__(256) void zero_cnt_kernel(
    unsigned* __restrict__ p, int n_u32)
{
    const int i = blockIdx.x * 256 + threadIdx.x;
    if (i < n_u32) p[i] = 0u;
}

// ---------------------------------------------------------------------------
// Kernel 1: x16 = bf16(feat @ W) via MFMA. Proven 27us. (Round-13 lesson:
//   do NOT fuse this with part1 — shared regalloc collapsed its 16-load
//   prefetch batch, 47us serial -> 82us fused.)
// ---------------------------------------------------------------------------
__global__ __launch_bounds__(256) void gemm_mfma_kernel(
    const float* __restrict__ feat,
    const float* __restrict__ W,
    unsigned short* __restrict__ x16,
    int n)
{
    __shared__ short sWT[OUT_FEAT][IN_FEAT + 8];

    const int tid = threadIdx.x;
    for (int i = tid; i < IN_FEAT * OUT_FEAT; i += 256) {
        const int k = i >> 5, c = i & 31;
        __hip_bfloat16 h = __float2bfloat16(W[i]);
        sWT[c][k] = *reinterpret_cast<short*>(&h);
    }
    __syncthreads();

    const int wid  = tid >> 6;
    const int lane = tid & 63;
    const int tile = blockIdx.x * 4 + wid;
    const int row0 = tile * 16;
    if (row0 >= n) return;

    const int l16 = lane & 15;
    const int lh  = lane >> 4;

    if (row0 + 16 <= n) {
        const int row = row0 + l16;
        const float4* fr = reinterpret_cast<const float4*>(feat) + (size_t)row * (IN_FEAT / 4);

        float4 ra[8][2];
        #pragma unroll
        for (int ks = 0; ks < 8; ++ks) {
            ra[ks][0] = fr[ks * 8 + lh * 2];
            ra[ks][1] = fr[ks * 8 + lh * 2 + 1];
        }

        f32x4 acc0 = {0.f, 0.f, 0.f, 0.f};
        f32x4 acc1 = {0.f, 0.f, 0.f, 0.f};

        #pragma unroll
        for (int ks = 0; ks < 8; ++ks) {
            union { short8 s; unsigned u[4]; } af;
            af.u[0] = cvt_pk_bf16(ra[ks][0].x, ra[ks][0].y);
            af.u[1] = cvt_pk_bf16(ra[ks][0].z, ra[ks][0].w);
            af.u[2] = cvt_pk_bf16(ra[ks][1].x, ra[ks][1].y);
            af.u[3] = cvt_pk_bf16(ra[ks][1].z, ra[ks][1].w);

            const int k0 = ks * 32 + lh * 8;
            short8 b0 = *reinterpret_cast<const short8*>(&sWT[l16][k0]);
            short8 b1 = *reinterpret_cast<const short8*>(&sWT[16 + l16][k0]);

            acc0 = __builtin_amdgcn_mfma_f32_16x16x32_bf16(af.s, b0, acc0, 0, 0, 0);
            acc1 = __builtin_amdgcn_mfma_f32_16x16x32_bf16(af.s, b1, acc1, 0, 0, 0);
        }

        #pragma unroll
        for (int r = 0; r < 4; ++r) {
            const size_t orow = (size_t)(row0 + lh * 4 + r) * OUT_FEAT;
            const unsigned pk = cvt_pk_bf16(acc0[r], acc1[r]);
            x16[orow + l16]      = (unsigned short)(pk & 0xFFFFu);
            x16[orow + 16 + l16] = (unsigned short)(pk >> 16);
        }
    } else {
        const int rows = n - row0;
        for (int idx = lane; idx < rows * OUT_FEAT; idx += 64) {
            const int r = idx >> 5, j = idx & 31;
            float a = 0.f;
            for (int k = 0; k < IN_FEAT; ++k) {
                unsigned wb = ((unsigned)(unsigned short)sWT[j][k]) << 16;
                a += feat[(size_t)(row0 + r) * IN_FEAT + k] * __uint_as_float(wb);
            }
            x16[(size_t)(row0 + r) * OUT_FEAT + j] =
                (unsigned short)(cvt_pk_bf16(a, 0.f) & 0xFFFFu);
        }
    }
}

// ---------------------------------------------------------------------------
// Kernel 2: partition edges into 128-row buckets (row>>7). Proven.
// ---------------------------------------------------------------------------
__global__ __launch_bounds__(512) void part1_kernel(
    const float* __restrict__ vals,
    const int* __restrict__ erow,
    const int* __restrict__ ecol,
    uint2* __restrict__ buf1,
    unsigned* __restrict__ cnt1,
    unsigned* __restrict__ ocnt,
    uint4* __restrict__ obuf,
    int n_edges, int nc)
{
    __shared__ uint2 sE[L1_CHUNK];                 // 32 KB
    __shared__ unsigned short sBkt[L1_CHUNK];      // 8 KB
    __shared__ unsigned sHist[NC_MAX], sBase[NC_MAX], sCur[NC_MAX], sGBase[NC_MAX];

    const int tid = threadIdx.x;
    const int chunk0 = blockIdx.x * L1_CHUNK;
    const int nq = n_edges >> 2;

    for (int b = tid; b < nc; b += 512) { sHist[b] = 0; sCur[b] = 0; }
    __syncthreads();

    int4 r4[2]; int4 c4[2]; float4 v4[2];
    #pragma unroll
    for (int i = 0; i < 2; ++i) {
        const int qi = (chunk0 >> 2) + tid + i * 512;
        if (qi < nq) {
            r4[i] = reinterpret_cast<const int4*>(erow)[qi];
            c4[i] = reinterpret_cast<const int4*>(ecol)[qi];
            v4[i] = reinterpret_cast<const float4*>(vals)[qi];
        } else {
            r4[i] = make_int4(-1, -1, -1, -1);
            c4[i] = make_int4(0, 0, 0, 0);
            v4[i] = make_float4(0.f, 0.f, 0.f, 0.f);
        }
    }

    #pragma unroll
    for (int i = 0; i < 2; ++i) {
        const int* rr = &r4[i].x;
        #pragma unroll
        for (int t = 0; t < 4; ++t)
            if (rr[t] >= 0) atomicAdd(&sHist[rr[t] >> 7], 1u);
    }
    __syncthreads();

    if (tid == 0) {
        unsigned s = 0;
        for (int b = 0; b < nc; ++b) { sBase[b] = s; s += sHist[b]; }
    }
    __syncthreads();

    for (int b = tid; b < nc; b += 512)
        sGBase[b] = sHist[b] ? atomicAdd(&cnt1[(size_t)b * CNT_STRIDE], sHist[b]) : 0u;
    __syncthreads();

    #pragma unroll
    for (int i = 0; i < 2; ++i) {
        const int*   rr = &r4[i].x;
        const int*   cc = &c4[i].x;
        const float* vv = &v4[i].x;
        #pragma unroll
        for (int t = 0; t < 4; ++t) {
            const int r = rr[t];
            if (r >= 0) {
                const int cb = r >> 7;
                unsigned p = sBase[cb] + atomicAdd(&sCur[cb], 1u);
                sE[p] = make_uint2(((unsigned)(r & 127) << 17) | (unsigned)cc[t],
                                   __float_as_uint(vv[t]));
                sBkt[p] = (unsigned short)cb;
            }
        }
    }
    __syncthreads();

    int total = n_edges - chunk0;
    if (total > L1_CHUNK) total = L1_CHUNK;
    for (int p = tid; p < total; p += 512) {
        const int cb = sBkt[p];
        const unsigned g = sGBase[cb] + (p - sBase[cb]);
        const uint2 e = sE[p];
        if (g < CAPC) {
            buf1[(size_t)cb * CAPC + g] = e;
        } else {
            unsigned o = atomicAdd(ocnt, 1u);
            if (o < OCAP)
                obuf[o] = make_uint4(((unsigned)cb << 7) | (e.x >> 17),
                                     e.x & 0x1FFFFu, e.y, 0u);
        }
    }

    if (blockIdx.x == 0 && tid < (n_edges & 3)) {
        const int e = (nq << 2) + tid;
        unsigned o = atomicAdd(ocnt, 1u);
        if (o < OCAP)
            obuf[o] = make_uint4((unsigned)erow[e], (unsigned)ecol[e],
                                 __float_as_uint(vals[e]), 0u);
    }
}

// ---------------------------------------------------------------------------
// Kernel 3: in-place counting sort of each bucket by local row + CSR emit.
// ---------------------------------------------------------------------------
__global__ __launch_bounds__(512) void sort_kernel(
    uint2* __restrict__ buf1,
    const unsigned* __restrict__ cnt1,
    unsigned* __restrict__ rstart,
    unsigned* __restrict__ rcnt)
{
    __shared__ uint2 sorted[CAPC];                       // 20 KB
    __shared__ unsigned h[RBC], base[RBC], cur[RBC];

    const int tid = threadIdx.x;
    const int b = blockIdx.x;
    unsigned n = cnt1[(size_t)b * CNT_STRIDE];
    if (n > CAPC) n = CAPC;
    uint2* eb = buf1 + (size_t)b * CAPC;

    if (tid < RBC) { h[tid] = 0; cur[tid] = 0; }
    __syncthreads();

    uint2 e[5];   // 5*512 = 2560 = CAPC
    #pragma unroll
    for (int i = 0; i < 5; ++i) {
        const int p = tid + i * 512;
        e[i] = (p < (int)n) ? eb[p] : make_uint2(0xFFFFFFFFu, 0u);
    }
    #pragma unroll
    for (int i = 0; i < 5; ++i)
        if (e[i].x != 0xFFFFFFFFu) atomicAdd(&h[(e[i].x >> 17) & 127u], 1u);
    __syncthreads();

    if (tid == 0) {
        unsigned s = 0;
        for (int r = 0; r < RBC; ++r) { base[r] = s; s += h[r]; }
    }
    __syncthreads();

    #pragma unroll
    for (int i = 0; i < 5; ++i) {
        if (e[i].x != 0xFFFFFFFFu) {
            const unsigned r = (e[i].x >> 17) & 127u;
            const unsigned p = base[r] + atomicAdd(&cur[r], 1u);
            sorted[p] = e[i];
        }
    }
    __syncthreads();

    for (int i = tid; i < (int)n; i += 512) eb[i] = sorted[i];

    if (tid < RBC) {
        rstart[b * RBC + tid] = (unsigned)(b * CAPC) + base[tid];
        rcnt[b * RBC + tid]   = h[tid];
    }
}

// ---------------------------------------------------------------------------
// Kernel 4: CSR row-gather SpMM, 8-deep gather batch.
//   Wave = 4 slots x 16 lanes; slot preloads ALL its entries (8 covers
//   cn<=32 ~ every Poisson(16) row), then issues all gathers as one
//   independent batch -> ONE latency round/row instead of two.
//   launch_bounds(256,4) -> 128-VGPR budget so the batch stays live.
//   Zero atomics, zero LDS; oflow folded as trailing blocks.
// ---------------------------------------------------------------------------
__global__ __launch_bounds__(256, 4) void row_spmm_kernel(
    const uint2* __restrict__ buf1,
    const unsigned* __restrict__ rstart,
    const unsigned* __restrict__ rcnt,
    const unsigned* __restrict__ xw,   // x bf16, read as uints (16/row)
    float* __restrict__ out,
    int n_nodes, int nrow_blocks,
    const uint4* __restrict__ obuf,
    const unsigned* __restrict__ ocnt)
{
    if ((int)blockIdx.x >= nrow_blocks) {
        // ---- overflow cleanup (expected zero work) ----
        unsigned n = *ocnt;
        if (n > OCAP) n = OCAP;
        const long long total = (long long)n * OUT_FEAT;
        const long long stride = (long long)OBLK * 256;
        const unsigned short* x16 = (const unsigned short*)xw;
        for (long long idx = ((long long)blockIdx.x - nrow_blocks) * 256 + threadIdx.x;
             idx < total; idx += stride) {
            const int e = (int)(idx >> 5), j = (int)(idx & 31);
            uint4 p = obuf[e];
            atomicAdd(&out[(size_t)p.x * OUT_FEAT + j],
                      __uint_as_float(p.z) * bf16s(x16[(size_t)p.y * OUT_FEAT + j]));
        }
        return;
    }

    const int wid  = threadIdx.x >> 6;
    const int lane = threadIdx.x & 63;
    const int row  = blockIdx.x * 4 + wid;
    if (row >= n_nodes) return;

    const unsigned s  = rstart[row];
    const unsigned cn = rcnt[row];
    const int slot = lane >> 4;      // 0..3
    const int jp   = lane & 15;      // feature pair

    // Phase 1: preload entries (broadcast within slot, L1/L2-resident).
    uint2 p[8];
    #pragma unroll
    for (int i = 0; i < 8; ++i) {
        const unsigned e = (unsigned)slot + 4u * (unsigned)i;
        p[i] = (e < cn) ? buf1[s + e] : make_uint2(0u, 0u);   // val=0 -> no-op
    }

    // Phase 2: all gathers issued as one independent batch.
    unsigned w[8];
    #pragma unroll
    for (int i = 0; i < 8; ++i) {
        const unsigned e = (unsigned)slot + 4u * (unsigned)i;
        w[i] = (e < cn) ? xw[(size_t)(p[i].x & 0x1FFFFu) * 16 + jp] : 0u;
    }

    // Phase 3: FMA reduction in registers.
    float aLo = 0.f, aHi = 0.f;
    #pragma unroll
    for (int i = 0; i < 8; ++i) {
        const float v = __uint_as_float(p[i].y);
        aLo += v * bf16lo(w[i]);
        aHi += v * bf16hi(w[i]);
    }

    // tail for rare rows with cn > 32
    for (unsigned e = 32u + (unsigned)slot; e < cn; e += 4) {
        const uint2 q = buf1[s + e];
        const unsigned ww = xw[(size_t)(q.x & 0x1FFFFu) * 16 + jp];
        const float v = __uint_as_float(q.y);
        aLo += v * bf16lo(ww);
        aHi += v * bf16hi(ww);
    }

    aLo += __shfl_down(aLo, 32, 64);
    aHi += __shfl_down(aHi, 32, 64);
    aLo += __shfl_down(aLo, 16, 64);
    aHi += __shfl_down(aHi, 16, 64);

    if (slot == 0) {
        float2 v = make_float2(aLo, aHi);
        *reinterpret_cast<float2*>(&out[(size_t)row * OUT_FEAT + 2 * jp]) = v;
    }
}

// ---------------------------------------------------------------------------
// Fallback path (ws/shape gate fails): fp32 gemm + flat atomic scatter.
// ---------------------------------------------------------------------------
__global__ __launch_bounds__(256) void gemm_f32_fallback_kernel(
    const float* __restrict__ feat, const float* __restrict__ W,
    float* __restrict__ x, int n)
{
    const long long idx = (long long)blockIdx.x * 256 + threadIdx.x;
    if (idx >= (long long)n * OUT_FEAT) return;
    const int r = (int)(idx >> 5), j = (int)(idx & 31);
    float a = 0.f;
    for (int k = 0; k < IN_FEAT; ++k)
        a += feat[(size_t)r * IN_FEAT + k] * W[k * OUT_FEAT + j];
    x[idx] = a;
}

__global__ __launch_bounds__(256) void spmm_scatter_kernel(
    const float* __restrict__ vals,
    const int* __restrict__ erow,
    const int* __restrict__ ecol,
    const float* __restrict__ x,
    float* __restrict__ out,
    int n_edges)
{
    const long long idx = (long long)blockIdx.x * blockDim.x + threadIdx.x;
    const int e = (int)(idx >> 5);
    const int j = (int)(idx & 31);
    if (e >= n_edges) return;
    const float m = vals[e] * x[(size_t)ecol[e] * OUT_FEAT + j];
    atomicAdd(&out[(size_t)erow[e] * OUT_FEAT + j], m);
}

// ---------------------------------------------------------------------------
extern "C" void kernel_launch(void* const* d_in, const int* in_sizes, int n_in,
                              void* d_out, int out_size, void* d_ws, size_t ws_size,
                              hipStream_t stream)
{
    const float* feat = (const float*)d_in[0];
    const float* W    = (const float*)d_in[1];
    const float* vals = (const float*)d_in[2];
    const int*   erow = (const int*)d_in[3];
    const int*   ecol = (const int*)d_in[4];
    float* out = (float*)d_out;

    const int n_nodes = in_sizes[0] / IN_FEAT;
    const int n_edges = in_sizes[2];
    const int nc = (n_nodes + RBC - 1) / RBC;     // 782 buckets

    char* ws = (char*)d_ws;
    size_t off = 0;
    auto alloc = [&](size_t bytes) { size_t o = off; off = (off + bytes + 15) & ~(size_t)15; return o; };
    unsigned short* x16 = (unsigned short*)(ws + alloc((size_t)n_nodes * OUT_FEAT * sizeof(unsigned short)));
    uint2*    buf1   = (uint2*)(ws + alloc((size_t)nc * CAPC * sizeof(uint2)));
    unsigned* cnt1   = (unsigned*)(ws + alloc((size_t)nc * CNT_STRIDE * sizeof(unsigned)));
    unsigned* ocnt   = (unsigned*)(ws + alloc(sizeof(unsigned)));
    unsigned* rstart = (unsigned*)(ws + alloc((size_t)nc * RBC * sizeof(unsigned)));
    unsigned* rcnt   = (unsigned*)(ws + alloc((size_t)nc * RBC * sizeof(unsigned)));
    uint4*    obuf   = (uint4*)(ws + alloc((size_t)OCAP * sizeof(uint4)));

    const double lam = (nc > 0) ? (double)n_edges / nc : 0.0;
    const bool sorted_path = (ws_size >= off) && (nc <= NC_MAX) &&
                             (lam + 8.0 * sqrt(lam + 1.0) <= (double)CAPC);

    if (sorted_path) {
        // 1) gemm (independent of 2-3; separate kernels — round-13 lesson)
        const int tiles = (n_nodes + 15) / 16;
        gemm_mfma_kernel<<<(tiles + 3) / 4, 256, 0, stream>>>(feat, W, x16, n_nodes);

        // zero cnt1 + ocnt (contiguous)
        const int zn = nc * CNT_STRIDE + 4;
        zero_cnt_kernel<<<(zn + 255) / 256, 256, 0, stream>>>(cnt1, zn);

        // 2) partition into 128-row buckets
        const int nblk = (n_edges + L1_CHUNK - 1) / L1_CHUNK;
        part1_kernel<<<nblk, 512, 0, stream>>>(vals, erow, ecol, buf1, cnt1,
                                               ocnt, obuf, n_edges, nc);
        // 3) per-bucket row sort + CSR pointers
        sort_kernel<<<nc, 512, 0, stream>>>(buf1, cnt1, rstart, rcnt);

        // 4) CSR row-gather SpMM (+ oflow tail blocks)
        const int nrow_blocks = (n_nodes + 3) / 4;
        row_spmm_kernel<<<nrow_blocks + OBLK, 256, 0, stream>>>(
            buf1, rstart, rcnt, (const unsigned*)x16, out, n_nodes,
            nrow_blocks, obuf, ocnt);
    } else {
        float* xf = (float*)d_ws;
        hipMemsetAsync(d_out, 0, (size_t)out_size * sizeof(float), stream);
        long long xtot = (long long)n_nodes * OUT_FEAT;
        gemm_f32_fallback_kernel<<<(unsigned)((xtot + 255) / 256), 256, 0, stream>>>(
            feat, W, xf, n_nodes);
        long long total = (long long)n_edges * OUT_FEAT;
        spmm_scatter_kernel<<<(unsigned)((total + 255) / 256), 256, 0, stream>>>(
            vals, erow, ecol, xf, out, n_edges);
    }
}

// Round 15
// 88.267 us; speedup vs baseline: 1.3819x; 1.2336x over previous
//
#include <hip/hip_runtime.h>
#include <hip/hip_bf16.h>

#define IN_FEAT 256
#define OUT_FEAT 32

#define RBC 128          // rows per bucket
#define NC_MAX 1024      // max buckets (n_nodes <= 131072)
#define CAPC 2560        // capacity per bucket: lambda=2046 (+11 sigma)
#define L1_CHUNK 4096    // edges per part1 block (8/thread, 512 threads)
#define OCAP 16384       // overflow list capacity
#define CNT_STRIDE 16    // u32 stride between counters (64B apart)
#define OBLK 64          // oflow blocks appended to sort_consume grid

typedef __attribute__((ext_vector_type(8))) short short8;
typedef __attribute__((ext_vector_type(4))) float f32x4;

__device__ __forceinline__ unsigned cvt_pk_bf16(float lo, float hi) {
    unsigned r;
    asm volatile("v_cvt_pk_bf16_f32 %0, %1, %2" : "=v"(r) : "v"(lo), "v"(hi));
    return r;
}
__device__ __forceinline__ float bf16lo(unsigned w) { return __uint_as_float(w << 16); }
__device__ __forceinline__ float bf16hi(unsigned w) { return __uint_as_float(w & 0xFFFF0000u); }
__device__ __forceinline__ float bf16s(unsigned short u) { return __uint_as_float(((unsigned)u) << 16); }

// ---------------------------------------------------------------------------
// Kernel 0: zero bucket counters + overflow counter.
// ---------------------------------------------------------------------------
__global__ __launch_bounds__(256) void zero_cnt_kernel(
    unsigned* __restrict__ p, int n_u32)
{
    const int i = blockIdx.x * 256 + threadIdx.x;
    if (i < n_u32) p[i] = 0u;
}

// ---------------------------------------------------------------------------
// Kernel 1: x16 = bf16(feat @ W) via MFMA. Proven 27us. Not fused with
//   anything (round-13 lesson: shared regalloc collapses its prefetch).
// ---------------------------------------------------------------------------
__global__ __launch_bounds__(256) void gemm_mfma_kernel(
    const float* __restrict__ feat,
    const float* __restrict__ W,
    unsigned short* __restrict__ x16,
    int n)
{
    __shared__ short sWT[OUT_FEAT][IN_FEAT + 8];

    const int tid = threadIdx.x;
    for (int i = tid; i < IN_FEAT * OUT_FEAT; i += 256) {
        const int k = i >> 5, c = i & 31;
        __hip_bfloat16 h = __float2bfloat16(W[i]);
        sWT[c][k] = *reinterpret_cast<short*>(&h);
    }
    __syncthreads();

    const int wid  = tid >> 6;
    const int lane = tid & 63;
    const int tile = blockIdx.x * 4 + wid;
    const int row0 = tile * 16;
    if (row0 >= n) return;

    const int l16 = lane & 15;
    const int lh  = lane >> 4;

    if (row0 + 16 <= n) {
        const int row = row0 + l16;
        const float4* fr = reinterpret_cast<const float4*>(feat) + (size_t)row * (IN_FEAT / 4);

        float4 ra[8][2];
        #pragma unroll
        for (int ks = 0; ks < 8; ++ks) {
            ra[ks][0] = fr[ks * 8 + lh * 2];
            ra[ks][1] = fr[ks * 8 + lh * 2 + 1];
        }

        f32x4 acc0 = {0.f, 0.f, 0.f, 0.f};
        f32x4 acc1 = {0.f, 0.f, 0.f, 0.f};

        #pragma unroll
        for (int ks = 0; ks < 8; ++ks) {
            union { short8 s; unsigned u[4]; } af;
            af.u[0] = cvt_pk_bf16(ra[ks][0].x, ra[ks][0].y);
            af.u[1] = cvt_pk_bf16(ra[ks][0].z, ra[ks][0].w);
            af.u[2] = cvt_pk_bf16(ra[ks][1].x, ra[ks][1].y);
            af.u[3] = cvt_pk_bf16(ra[ks][1].z, ra[ks][1].w);

            const int k0 = ks * 32 + lh * 8;
            short8 b0 = *reinterpret_cast<const short8*>(&sWT[l16][k0]);
            short8 b1 = *reinterpret_cast<const short8*>(&sWT[16 + l16][k0]);

            acc0 = __builtin_amdgcn_mfma_f32_16x16x32_bf16(af.s, b0, acc0, 0, 0, 0);
            acc1 = __builtin_amdgcn_mfma_f32_16x16x32_bf16(af.s, b1, acc1, 0, 0, 0);
        }

        #pragma unroll
        for (int r = 0; r < 4; ++r) {
            const size_t orow = (size_t)(row0 + lh * 4 + r) * OUT_FEAT;
            const unsigned pk = cvt_pk_bf16(acc0[r], acc1[r]);
            x16[orow + l16]      = (unsigned short)(pk & 0xFFFFu);
            x16[orow + 16 + l16] = (unsigned short)(pk >> 16);
        }
    } else {
        const int rows = n - row0;
        for (int idx = lane; idx < rows * OUT_FEAT; idx += 64) {
            const int r = idx >> 5, j = idx & 31;
            float a = 0.f;
            for (int k = 0; k < IN_FEAT; ++k) {
                unsigned wb = ((unsigned)(unsigned short)sWT[j][k]) << 16;
                a += feat[(size_t)(row0 + r) * IN_FEAT + k] * __uint_as_float(wb);
            }
            x16[(size_t)(row0 + r) * OUT_FEAT + j] =
                (unsigned short)(cvt_pk_bf16(a, 0.f) & 0xFFFFu);
        }
    }
}

// ---------------------------------------------------------------------------
// Kernel 2: partition edges into 128-row buckets (row>>7). Proven.
// ---------------------------------------------------------------------------
__global__ __launch_bounds__(512) void part1_kernel(
    const float* __restrict__ vals,
    const int* __restrict__ erow,
    const int* __restrict__ ecol,
    uint2* __restrict__ buf1,
    unsigned* __restrict__ cnt1,
    unsigned* __restrict__ ocnt,
    uint4* __restrict__ obuf,
    int n_edges, int nc)
{
    __shared__ uint2 sE[L1_CHUNK];                 // 32 KB
    __shared__ unsigned short sBkt[L1_CHUNK];      // 8 KB
    __shared__ unsigned sHist[NC_MAX], sBase[NC_MAX], sCur[NC_MAX], sGBase[NC_MAX];

    const int tid = threadIdx.x;
    const int chunk0 = blockIdx.x * L1_CHUNK;
    const int nq = n_edges >> 2;

    for (int b = tid; b < nc; b += 512) { sHist[b] = 0; sCur[b] = 0; }
    __syncthreads();

    int4 r4[2]; int4 c4[2]; float4 v4[2];
    #pragma unroll
    for (int i = 0; i < 2; ++i) {
        const int qi = (chunk0 >> 2) + tid + i * 512;
        if (qi < nq) {
            r4[i] = reinterpret_cast<const int4*>(erow)[qi];
            c4[i] = reinterpret_cast<const int4*>(ecol)[qi];
            v4[i] = reinterpret_cast<const float4*>(vals)[qi];
        } else {
            r4[i] = make_int4(-1, -1, -1, -1);
            c4[i] = make_int4(0, 0, 0, 0);
            v4[i] = make_float4(0.f, 0.f, 0.f, 0.f);
        }
    }

    #pragma unroll
    for (int i = 0; i < 2; ++i) {
        const int* rr = &r4[i].x;
        #pragma unroll
        for (int t = 0; t < 4; ++t)
            if (rr[t] >= 0) atomicAdd(&sHist[rr[t] >> 7], 1u);
    }
    __syncthreads();

    if (tid == 0) {
        unsigned s = 0;
        for (int b = 0; b < nc; ++b) { sBase[b] = s; s += sHist[b]; }
    }
    __syncthreads();

    for (int b = tid; b < nc; b += 512)
        sGBase[b] = sHist[b] ? atomicAdd(&cnt1[(size_t)b * CNT_STRIDE], sHist[b]) : 0u;
    __syncthreads();

    #pragma unroll
    for (int i = 0; i < 2; ++i) {
        const int*   rr = &r4[i].x;
        const int*   cc = &c4[i].x;
        const float* vv = &v4[i].x;
        #pragma unroll
        for (int t = 0; t < 4; ++t) {
            const int r = rr[t];
            if (r >= 0) {
                const int cb = r >> 7;
                unsigned p = sBase[cb] + atomicAdd(&sCur[cb], 1u);
                sE[p] = make_uint2(((unsigned)(r & 127) << 17) | (unsigned)cc[t],
                                   __float_as_uint(vv[t]));
                sBkt[p] = (unsigned short)cb;
            }
        }
    }
    __syncthreads();

    int total = n_edges - chunk0;
    if (total > L1_CHUNK) total = L1_CHUNK;
    for (int p = tid; p < total; p += 512) {
        const int cb = sBkt[p];
        const unsigned g = sGBase[cb] + (p - sBase[cb]);
        const uint2 e = sE[p];
        if (g < CAPC) {
            buf1[(size_t)cb * CAPC + g] = e;
        } else {
            unsigned o = atomicAdd(ocnt, 1u);
            if (o < OCAP)
                obuf[o] = make_uint4(((unsigned)cb << 7) | (e.x >> 17),
                                     e.x & 0x1FFFFu, e.y, 0u);
        }
    }

    if (blockIdx.x == 0 && tid < (n_edges & 3)) {
        const int e = (nq << 2) + tid;
        unsigned o = atomicAdd(ocnt, 1u);
        if (o < OCAP)
            obuf[o] = make_uint4((unsigned)erow[e], (unsigned)ecol[e],
                                 __float_as_uint(vals[e]), 0u);
    }
}

// ---------------------------------------------------------------------------
// Kernel 3: FUSED sort + consume (sequential phases, one block per bucket).
//   Phase 1: proven LDS counting sort (no global write-back — saves the
//   12.8MB rewrite + 12.8MB re-read + rstart/rcnt of the split version).
//   Phase 2: 8 waves x 16 rows; entries from LDS (broadcast, free),
//   8-deep gather batch from global, register FMA, shfl reduce, plain
//   128B row store (full coverage -> no out memset). Zero global atomics.
//   oflow cleanup folded as OBLK trailing blocks.
// ---------------------------------------------------------------------------
__global__ __launch_bounds__(512) void sort_consume_kernel(
    uint2* __restrict__ buf1,
    const unsigned* __restrict__ cnt1,
    const unsigned* __restrict__ xw,   // x bf16, read as uints (16/row)
    float* __restrict__ out,
    int n_nodes, int nc,
    const uint4* __restrict__ obuf,
    const unsigned* __restrict__ ocnt)
{
    if ((int)blockIdx.x >= nc) {
        // ---- overflow cleanup (expected zero work) ----
        unsigned n = *ocnt;
        if (n > OCAP) n = OCAP;
        const long long total = (long long)n * OUT_FEAT;
        const long long stride = (long long)OBLK * 512;
        const unsigned short* x16 = (const unsigned short*)xw;
        for (long long idx = ((long long)blockIdx.x - nc) * 512 + threadIdx.x;
             idx < total; idx += stride) {
            const int e = (int)(idx >> 5), j = (int)(idx & 31);
            uint4 p = obuf[e];
            atomicAdd(&out[(size_t)p.x * OUT_FEAT + j],
                      __uint_as_float(p.z) * bf16s(x16[(size_t)p.y * OUT_FEAT + j]));
        }
        return;
    }

    __shared__ uint2 sorted[CAPC];                       // 20 KB
    __shared__ unsigned h[RBC], base[RBC], cur[RBC];     // 1.5 KB

    const int tid = threadIdx.x;
    const int b = blockIdx.x;
    unsigned n = cnt1[(size_t)b * CNT_STRIDE];
    if (n > CAPC) n = CAPC;
    const uint2* eb = buf1 + (size_t)b * CAPC;

    // ---------- Phase 1: counting sort into LDS (proven structure) ----------
    if (tid < RBC) { h[tid] = 0; cur[tid] = 0; }
    __syncthreads();

    uint2 e[5];   // 5*512 = 2560 = CAPC
    #pragma unroll
    for (int i = 0; i < 5; ++i) {
        const int p = tid + i * 512;
        e[i] = (p < (int)n) ? eb[p] : make_uint2(0xFFFFFFFFu, 0u);
    }
    #pragma unroll
    for (int i = 0; i < 5; ++i)
        if (e[i].x != 0xFFFFFFFFu) atomicAdd(&h[(e[i].x >> 17) & 127u], 1u);
    __syncthreads();

    if (tid == 0) {
        unsigned s = 0;
        for (int r = 0; r < RBC; ++r) { base[r] = s; s += h[r]; }
    }
    __syncthreads();

    #pragma unroll
    for (int i = 0; i < 5; ++i) {
        if (e[i].x != 0xFFFFFFFFu) {
            const unsigned r = (e[i].x >> 17) & 127u;
            const unsigned p = base[r] + atomicAdd(&cur[r], 1u);
            sorted[p] = e[i];
        }
    }
    __syncthreads();

    // ---------- Phase 2: per-row register-accumulating consume ----------
    const int wid  = tid >> 6;        // wave 0..7
    const int lane = tid & 63;
    const int slot = lane >> 4;       // 0..3
    const int jp   = lane & 15;       // feature pair

    const int rowBase = b * RBC;
    #pragma unroll 1
    for (int rl = wid * 16; rl < wid * 16 + 16; ++rl) {
        const int row = rowBase + rl;
        if (row >= n_nodes) break;

        const unsigned st = base[rl];
        const unsigned cn = h[rl];

        // preload entries from LDS (broadcast within 16-lane groups)
        uint2 p[8];
        #pragma unroll
        for (int i = 0; i < 8; ++i) {
            const unsigned ee = (unsigned)slot + 4u * (unsigned)i;
            p[i] = (ee < cn) ? sorted[st + ee] : make_uint2(0u, 0u);  // val=0 -> no-op
        }

        // one independent gather batch
        unsigned w[8];
        #pragma unroll
        for (int i = 0; i < 8; ++i) {
            const unsigned ee = (unsigned)slot + 4u * (unsigned)i;
            w[i] = (ee < cn) ? xw[(size_t)(p[i].x & 0x1FFFFu) * 16 + jp] : 0u;
        }

        float aLo = 0.f, aHi = 0.f;
        #pragma unroll
        for (int i = 0; i < 8; ++i) {
            const float v = __uint_as_float(p[i].y);
            aLo += v * bf16lo(w[i]);
            aHi += v * bf16hi(w[i]);
        }

        // rare tail (cn > 32), entries still in LDS
        for (unsigned ee = 32u + (unsigned)slot; ee < cn; ee += 4) {
            const uint2 q = sorted[st + ee];
            const unsigned ww = xw[(size_t)(q.x & 0x1FFFFu) * 16 + jp];
            const float v = __uint_as_float(q.y);
            aLo += v * bf16lo(ww);
            aHi += v * bf16hi(ww);
        }

        aLo += __shfl_down(aLo, 32, 64);
        aHi += __shfl_down(aHi, 32, 64);
        aLo += __shfl_down(aLo, 16, 64);
        aHi += __shfl_down(aHi, 16, 64);

        if (slot == 0) {
            float2 v = make_float2(aLo, aHi);
            *reinterpret_cast<float2*>(&out[(size_t)row * OUT_FEAT + 2 * jp]) = v;
        }
    }
}

// ---------------------------------------------------------------------------
// Fallback path (ws/shape gate fails): fp32 gemm + flat atomic scatter.
// ---------------------------------------------------------------------------
__global__ __launch_bounds__(256) void gemm_f32_fallback_kernel(
    const float* __restrict__ feat, const float* __restrict__ W,
    float* __restrict__ x, int n)
{
    const long long idx = (long long)blockIdx.x * 256 + threadIdx.x;
    if (idx >= (long long)n * OUT_FEAT) return;
    const int r = (int)(idx >> 5), j = (int)(idx & 31);
    float a = 0.f;
    for (int k = 0; k < IN_FEAT; ++k)
        a += feat[(size_t)r * IN_FEAT + k] * W[k * OUT_FEAT + j];
    x[idx] = a;
}

__global__ __launch_bounds__(256) void spmm_scatter_kernel(
    const float* __restrict__ vals,
    const int* __restrict__ erow,
    const int* __restrict__ ecol,
    const float* __restrict__ x,
    float* __restrict__ out,
    int n_edges)
{
    const long long idx = (long long)blockIdx.x * blockDim.x + threadIdx.x;
    const int e = (int)(idx >> 5);
    const int j = (int)(idx & 31);
    if (e >= n_edges) return;
    const float m = vals[e] * x[(size_t)ecol[e] * OUT_FEAT + j];
    atomicAdd(&out[(size_t)erow[e] * OUT_FEAT + j], m);
}

// ---------------------------------------------------------------------------
extern "C" void kernel_launch(void* const* d_in, const int* in_sizes, int n_in,
                              void* d_out, int out_size, void* d_ws, size_t ws_size,
                              hipStream_t stream)
{
    const float* feat = (const float*)d_in[0];
    const float* W    = (const float*)d_in[1];
    const float* vals = (const float*)d_in[2];
    const int*   erow = (const int*)d_in[3];
    const int*   ecol = (const int*)d_in[4];
    float* out = (float*)d_out;

    const int n_nodes = in_sizes[0] / IN_FEAT;
    const int n_edges = in_sizes[2];
    const int nc = (n_nodes + RBC - 1) / RBC;     // 782 buckets

    char* ws = (char*)d_ws;
    size_t off = 0;
    auto alloc = [&](size_t bytes) { size_t o = off; off = (off + bytes + 15) & ~(size_t)15; return o; };
    unsigned short* x16 = (unsigned short*)(ws + alloc((size_t)n_nodes * OUT_FEAT * sizeof(unsigned short)));
    uint2*    buf1   = (uint2*)(ws + alloc((size_t)nc * CAPC * sizeof(uint2)));
    unsigned* cnt1   = (unsigned*)(ws + alloc((size_t)nc * CNT_STRIDE * sizeof(unsigned)));
    unsigned* ocnt   = (unsigned*)(ws + alloc(sizeof(unsigned)));
    uint4*    obuf   = (uint4*)(ws + alloc((size_t)OCAP * sizeof(uint4)));

    const double lam = (nc > 0) ? (double)n_edges / nc : 0.0;
    const bool sorted_path = (ws_size >= off) && (nc <= NC_MAX) &&
                             (lam + 8.0 * sqrt(lam + 1.0) <= (double)CAPC);

    if (sorted_path) {
        // 1) gemm
        const int tiles = (n_nodes + 15) / 16;
        gemm_mfma_kernel<<<(tiles + 3) / 4, 256, 0, stream>>>(feat, W, x16, n_nodes);

        // zero cnt1 + ocnt (contiguous)
        const int zn = nc * CNT_STRIDE + 4;
        zero_cnt_kernel<<<(zn + 255) / 256, 256, 0, stream>>>(cnt1, zn);

        // 2) partition into 128-row buckets
        const int nblk = (n_edges + L1_CHUNK - 1) / L1_CHUNK;
        part1_kernel<<<nblk, 512, 0, stream>>>(vals, erow, ecol, buf1, cnt1,
                                               ocnt, obuf, n_edges, nc);

        // 3) fused sort + consume (+ oflow tail blocks)
        sort_consume_kernel<<<nc + OBLK, 512, 0, stream>>>(
            buf1, cnt1, (const unsigned*)x16, out, n_nodes, nc, obuf, ocnt);
    } else {
        float* xf = (float*)d_ws;
        hipMemsetAsync(d_out, 0, (size_t)out_size * sizeof(float), stream);
        long long xtot = (long long)n_nodes * OUT_FEAT;
        gemm_f32_fallback_kernel<<<(unsigned)((xtot + 255) / 256), 256, 0, stream>>>(
            feat, W, xf, n_nodes);
        long long total = (long long)n_edges * OUT_FEAT;
        spmm_scatter_kernel<<<(unsigned)((total + 255) / 256), 256, 0, stream>>>(
            vals, erow, ecol, xf, out, n_edges);
    }
}

// Round 16
// 82.017 us; speedup vs baseline: 1.4872x; 1.0762x over previous
//
#include <hip/hip_runtime.h>
#include <hip/hip_bf16.h>

#define IN_FEAT 256
#define OUT_FEAT 32

#define RBC 128          // rows per bucket
#define NC_MAX 1024      // max buckets (n_nodes <= 131072)
#define CAPC 2560        // capacity per bucket: lambda=2046 (+11 sigma)
#define L1_CHUNK 4096    // edges per part1 block (8/thread, 512 threads)
#define OCAP 16384       // overflow list capacity
#define CNT_STRIDE 16    // u32 stride between counters (64B apart)
#define OBLK 64          // oflow blocks appended to sort_consume grid

typedef __attribute__((ext_vector_type(8))) short short8;
typedef __attribute__((ext_vector_type(4))) float f32x4;

__device__ __forceinline__ unsigned cvt_pk_bf16(float lo, float hi) {
    unsigned r;
    asm volatile("v_cvt_pk_bf16_f32 %0, %1, %2" : "=v"(r) : "v"(lo), "v"(hi));
    return r;
}
__device__ __forceinline__ float bf16lo(unsigned w) { return __uint_as_float(w << 16); }
__device__ __forceinline__ float bf16hi(unsigned w) { return __uint_as_float(w & 0xFFFF0000u); }
__device__ __forceinline__ float bf16s(unsigned short u) { return __uint_as_float(((unsigned)u) << 16); }

// ---------------------------------------------------------------------------
// Kernel 0: zero bucket counters + overflow counter.
// ---------------------------------------------------------------------------
__global__ __launch_bounds__(256) void zero_cnt_kernel(
    unsigned* __restrict__ p, int n_u32)
{
    const int i = blockIdx.x * 256 + threadIdx.x;
    if (i < n_u32) p[i] = 0u;
}

// ---------------------------------------------------------------------------
// Kernel 1: x16 = bf16(feat @ W) via MFMA. Proven 27us. Kept standalone
//   (round-13: fusing collapses its 16-load prefetch via shared regalloc).
// ---------------------------------------------------------------------------
__global__ __launch_bounds__(256) void gemm_mfma_kernel(
    const float* __restrict__ feat,
    const float* __restrict__ W,
    unsigned short* __restrict__ x16,
    int n)
{
    __shared__ short sWT[OUT_FEAT][IN_FEAT + 8];

    const int tid = threadIdx.x;
    for (int i = tid; i < IN_FEAT * OUT_FEAT; i += 256) {
        const int k = i >> 5, c = i & 31;
        __hip_bfloat16 h = __float2bfloat16(W[i]);
        sWT[c][k] = *reinterpret_cast<short*>(&h);
    }
    __syncthreads();

    const int wid  = tid >> 6;
    const int lane = tid & 63;
    const int tile = blockIdx.x * 4 + wid;
    const int row0 = tile * 16;
    if (row0 >= n) return;

    const int l16 = lane & 15;
    const int lh  = lane >> 4;

    if (row0 + 16 <= n) {
        const int row = row0 + l16;
        const float4* fr = reinterpret_cast<const float4*>(feat) + (size_t)row * (IN_FEAT / 4);

        float4 ra[8][2];
        #pragma unroll
        for (int ks = 0; ks < 8; ++ks) {
            ra[ks][0] = fr[ks * 8 + lh * 2];
            ra[ks][1] = fr[ks * 8 + lh * 2 + 1];
        }

        f32x4 acc0 = {0.f, 0.f, 0.f, 0.f};
        f32x4 acc1 = {0.f, 0.f, 0.f, 0.f};

        #pragma unroll
        for (int ks = 0; ks < 8; ++ks) {
            union { short8 s; unsigned u[4]; } af;
            af.u[0] = cvt_pk_bf16(ra[ks][0].x, ra[ks][0].y);
            af.u[1] = cvt_pk_bf16(ra[ks][0].z, ra[ks][0].w);
            af.u[2] = cvt_pk_bf16(ra[ks][1].x, ra[ks][1].y);
            af.u[3] = cvt_pk_bf16(ra[ks][1].z, ra[ks][1].w);

            const int k0 = ks * 32 + lh * 8;
            short8 b0 = *reinterpret_cast<const short8*>(&sWT[l16][k0]);
            short8 b1 = *reinterpret_cast<const short8*>(&sWT[16 + l16][k0]);

            acc0 = __builtin_amdgcn_mfma_f32_16x16x32_bf16(af.s, b0, acc0, 0, 0, 0);
            acc1 = __builtin_amdgcn_mfma_f32_16x16x32_bf16(af.s, b1, acc1, 0, 0, 0);
        }

        #pragma unroll
        for (int r = 0; r < 4; ++r) {
            const size_t orow = (size_t)(row0 + lh * 4 + r) * OUT_FEAT;
            const unsigned pk = cvt_pk_bf16(acc0[r], acc1[r]);
            x16[orow + l16]      = (unsigned short)(pk & 0xFFFFu);
            x16[orow + 16 + l16] = (unsigned short)(pk >> 16);
        }
    } else {
        const int rows = n - row0;
        for (int idx = lane; idx < rows * OUT_FEAT; idx += 64) {
            const int r = idx >> 5, j = idx & 31;
            float a = 0.f;
            for (int k = 0; k < IN_FEAT; ++k) {
                unsigned wb = ((unsigned)(unsigned short)sWT[j][k]) << 16;
                a += feat[(size_t)(row0 + r) * IN_FEAT + k] * __uint_as_float(wb);
            }
            x16[(size_t)(row0 + r) * OUT_FEAT + j] =
                (unsigned short)(cvt_pk_bf16(a, 0.f) & 0xFFFFu);
        }
    }
}

// ---------------------------------------------------------------------------
// Kernel 2: partition edges into 128-row buckets (row>>7), v2:
//   - parallel Hillis-Steele scan (10 steps) replaces thread-0's 782-iter
//     serial prefix (~3.3us on every block's critical path)
//   - 3 LDS arrays instead of 4 (position counters start at exclusive base;
//     copy-out recovers exclusive base from sScan[cb-1]): 52 KB -> 3 blk/CU.
// ---------------------------------------------------------------------------
__global__ __launch_bounds__(512) void part1_kernel(
    const float* __restrict__ vals,
    const int* __restrict__ erow,
    const int* __restrict__ ecol,
    uint2* __restrict__ buf1,
    unsigned* __restrict__ cnt1,
    unsigned* __restrict__ ocnt,
    uint4* __restrict__ obuf,
    int n_edges, int nc)
{
    __shared__ uint2 sE[L1_CHUNK];                 // 32 KB
    __shared__ unsigned short sBkt[L1_CHUNK];      // 8 KB
    __shared__ unsigned sCnt[NC_MAX], sScan[NC_MAX], sGBase[NC_MAX];  // 12 KB

    const int tid = threadIdx.x;
    const int chunk0 = blockIdx.x * L1_CHUNK;
    const int nq = n_edges >> 2;

    for (int b = tid; b < nc; b += 512) sCnt[b] = 0;
    __syncthreads();

    int4 r4[2]; int4 c4[2]; float4 v4[2];
    #pragma unroll
    for (int i = 0; i < 2; ++i) {
        const int qi = (chunk0 >> 2) + tid + i * 512;
        if (qi < nq) {
            r4[i] = reinterpret_cast<const int4*>(erow)[qi];
            c4[i] = reinterpret_cast<const int4*>(ecol)[qi];
            v4[i] = reinterpret_cast<const float4*>(vals)[qi];
        } else {
            r4[i] = make_int4(-1, -1, -1, -1);
            c4[i] = make_int4(0, 0, 0, 0);
            v4[i] = make_float4(0.f, 0.f, 0.f, 0.f);
        }
    }

    #pragma unroll
    for (int i = 0; i < 2; ++i) {
        const int* rr = &r4[i].x;
        #pragma unroll
        for (int t = 0; t < 4; ++t)
            if (rr[t] >= 0) atomicAdd(&sCnt[rr[t] >> 7], 1u);
    }
    __syncthreads();

    // Inclusive Hillis-Steele scan of sCnt -> sScan (parallel; 2 elems/thread).
    for (int b = tid; b < nc; b += 512) sScan[b] = sCnt[b];
    __syncthreads();
    for (int d = 1; d < nc; d <<= 1) {
        unsigned v0 = 0, v1 = 0;
        const int i0 = tid, i1 = tid + 512;
        if (i0 < nc && i0 >= d) v0 = sScan[i0 - d];
        if (i1 < nc && i1 >= d) v1 = sScan[i1 - d];
        __syncthreads();
        if (i0 < nc && i0 >= d) sScan[i0] += v0;
        if (i1 < nc && i1 >= d) sScan[i1] += v1;
        __syncthreads();
    }

    // Reserve global ranges + convert sCnt to exclusive-base position ctrs.
    for (int b = tid; b < nc; b += 512) {
        const unsigned c = sCnt[b];
        sGBase[b] = c ? atomicAdd(&cnt1[(size_t)b * CNT_STRIDE], c) : 0u;
        sCnt[b] = sScan[b] - c;   // exclusive base; counts up during placement
    }
    __syncthreads();

    #pragma unroll
    for (int i = 0; i < 2; ++i) {
        const int*   rr = &r4[i].x;
        const int*   cc = &c4[i].x;
        const float* vv = &v4[i].x;
        #pragma unroll
        for (int t = 0; t < 4; ++t) {
            const int r = rr[t];
            if (r >= 0) {
                const int cb = r >> 7;
                unsigned p = atomicAdd(&sCnt[cb], 1u);
                sE[p] = make_uint2(((unsigned)(r & 127) << 17) | (unsigned)cc[t],
                                   __float_as_uint(vv[t]));
                sBkt[p] = (unsigned short)cb;
            }
        }
    }
    __syncthreads();

    int total = n_edges - chunk0;
    if (total > L1_CHUNK) total = L1_CHUNK;
    for (int p = tid; p < total; p += 512) {
        const int cb = sBkt[p];
        const unsigned excl = cb ? sScan[cb - 1] : 0u;     // exclusive base (intact)
        const unsigned g = sGBase[cb] + ((unsigned)p - excl);
        const uint2 e = sE[p];
        if (g < CAPC) {
            buf1[(size_t)cb * CAPC + g] = e;
        } else {
            unsigned o = atomicAdd(ocnt, 1u);
            if (o < OCAP)
                obuf[o] = make_uint4(((unsigned)cb << 7) | (e.x >> 17),
                                     e.x & 0x1FFFFu, e.y, 0u);
        }
    }

    if (blockIdx.x == 0 && tid < (n_edges & 3)) {
        const int e = (nq << 2) + tid;
        unsigned o = atomicAdd(ocnt, 1u);
        if (o < OCAP)
            obuf[o] = make_uint4((unsigned)erow[e], (unsigned)ecol[e],
                                 __float_as_uint(vals[e]), 0u);
    }
}

// ---------------------------------------------------------------------------
// Kernel 3: FUSED sort + consume (proven, 88us-total structure), v2 with
//   parallel 128-entry scan replacing the thread-0 serial prefix.
// ---------------------------------------------------------------------------
__global__ __launch_bounds__(512) void sort_consume_kernel(
    uint2* __restrict__ buf1,
    const unsigned* __restrict__ cnt1,
    const unsigned* __restrict__ xw,   // x bf16, read as uints (16/row)
    float* __restrict__ out,
    int n_nodes, int nc,
    const uint4* __restrict__ obuf,
    const unsigned* __restrict__ ocnt)
{
    if ((int)blockIdx.x >= nc) {
        // ---- overflow cleanup (expected zero work) ----
        unsigned n = *ocnt;
        if (n > OCAP) n = OCAP;
        const long long total = (long long)n * OUT_FEAT;
        const long long stride = (long long)OBLK * 512;
        const unsigned short* x16 = (const unsigned short*)xw;
        for (long long idx = ((long long)blockIdx.x - nc) * 512 + threadIdx.x;
             idx < total; idx += stride) {
            const int e = (int)(idx >> 5), j = (int)(idx & 31);
            uint4 p = obuf[e];
            atomicAdd(&out[(size_t)p.x * OUT_FEAT + j],
                      __uint_as_float(p.z) * bf16s(x16[(size_t)p.y * OUT_FEAT + j]));
        }
        return;
    }

    __shared__ uint2 sorted[CAPC];                          // 20 KB
    __shared__ unsigned h[RBC], scan[RBC], cur[RBC];        // 1.5 KB

    const int tid = threadIdx.x;
    const int b = blockIdx.x;
    unsigned n = cnt1[(size_t)b * CNT_STRIDE];
    if (n > CAPC) n = CAPC;
    const uint2* eb = buf1 + (size_t)b * CAPC;

    // ---------- Phase 1: counting sort into LDS ----------
    if (tid < RBC) h[tid] = 0;
    __syncthreads();

    uint2 e[5];   // 5*512 = 2560 = CAPC
    #pragma unroll
    for (int i = 0; i < 5; ++i) {
        const int p = tid + i * 512;
        e[i] = (p < (int)n) ? eb[p] : make_uint2(0xFFFFFFFFu, 0u);
    }
    #pragma unroll
    for (int i = 0; i < 5; ++i)
        if (e[i].x != 0xFFFFFFFFu) atomicAdd(&h[(e[i].x >> 17) & 127u], 1u);
    __syncthreads();

    // parallel inclusive scan over 128 buckets (7 steps)
    if (tid < RBC) scan[tid] = h[tid];
    __syncthreads();
    #pragma unroll
    for (int d = 1; d < RBC; d <<= 1) {
        unsigned v = 0;
        if (tid < RBC && tid >= d) v = scan[tid - d];
        __syncthreads();
        if (tid < RBC && tid >= d) scan[tid] += v;
        __syncthreads();
    }
    if (tid < RBC) cur[tid] = scan[tid] - h[tid];   // exclusive base counters
    __syncthreads();

    #pragma unroll
    for (int i = 0; i < 5; ++i) {
        if (e[i].x != 0xFFFFFFFFu) {
            const unsigned r = (e[i].x >> 17) & 127u;
            const unsigned p = atomicAdd(&cur[r], 1u);
            sorted[p] = e[i];
        }
    }
    __syncthreads();

    // ---------- Phase 2: per-row register-accumulating consume ----------
    const int wid  = tid >> 6;        // wave 0..7
    const int lane = tid & 63;
    const int slot = lane >> 4;       // 0..3
    const int jp   = lane & 15;       // feature pair

    const int rowBase = b * RBC;
    #pragma unroll 1
    for (int rl = wid * 16; rl < wid * 16 + 16; ++rl) {
        const int row = rowBase + rl;
        if (row >= n_nodes) break;

        const unsigned cn = h[rl];
        const unsigned st = scan[rl] - cn;   // exclusive base (intact arrays)

        uint2 p[8];
        #pragma unroll
        for (int i = 0; i < 8; ++i) {
            const unsigned ee = (unsigned)slot + 4u * (unsigned)i;
            p[i] = (ee < cn) ? sorted[st + ee] : make_uint2(0u, 0u);
        }

        unsigned w[8];
        #pragma unroll
        for (int i = 0; i < 8; ++i) {
            const unsigned ee = (unsigned)slot + 4u * (unsigned)i;
            w[i] = (ee < cn) ? xw[(size_t)(p[i].x & 0x1FFFFu) * 16 + jp] : 0u;
        }

        float aLo = 0.f, aHi = 0.f;
        #pragma unroll
        for (int i = 0; i < 8; ++i) {
            const float v = __uint_as_float(p[i].y);
            aLo += v * bf16lo(w[i]);
            aHi += v * bf16hi(w[i]);
        }

        for (unsigned ee = 32u + (unsigned)slot; ee < cn; ee += 4) {
            const uint2 q = sorted[st + ee];
            const unsigned ww = xw[(size_t)(q.x & 0x1FFFFu) * 16 + jp];
            const float v = __uint_as_float(q.y);
            aLo += v * bf16lo(ww);
            aHi += v * bf16hi(ww);
        }

        aLo += __shfl_down(aLo, 32, 64);
        aHi += __shfl_down(aHi, 32, 64);
        aLo += __shfl_down(aLo, 16, 64);
        aHi += __shfl_down(aHi, 16, 64);

        if (slot == 0) {
            float2 v = make_float2(aLo, aHi);
            *reinterpret_cast<float2*>(&out[(size_t)row * OUT_FEAT + 2 * jp]) = v;
        }
    }
}

// ---------------------------------------------------------------------------
// Fallback path (ws/shape gate fails): fp32 gemm + flat atomic scatter.
// ---------------------------------------------------------------------------
__global__ __launch_bounds__(256) void gemm_f32_fallback_kernel(
    const float* __restrict__ feat, const float* __restrict__ W,
    float* __restrict__ x, int n)
{
    const long long idx = (long long)blockIdx.x * 256 + threadIdx.x;
    if (idx >= (long long)n * OUT_FEAT) return;
    const int r = (int)(idx >> 5), j = (int)(idx & 31);
    float a = 0.f;
    for (int k = 0; k < IN_FEAT; ++k)
        a += feat[(size_t)r * IN_FEAT + k] * W[k * OUT_FEAT + j];
    x[idx] = a;
}

__global__ __launch_bounds__(256) void spmm_scatter_kernel(
    const float* __restrict__ vals,
    const int* __restrict__ erow,
    const int* __restrict__ ecol,
    const float* __restrict__ x,
    float* __restrict__ out,
    int n_edges)
{
    const long long idx = (long long)blockIdx.x * blockDim.x + threadIdx.x;
    const int e = (int)(idx >> 5);
    const int j = (int)(idx & 31);
    if (e >= n_edges) return;
    const float m = vals[e] * x[(size_t)ecol[e] * OUT_FEAT + j];
    atomicAdd(&out[(size_t)erow[e] * OUT_FEAT + j], m);
}

// ---------------------------------------------------------------------------
extern "C" void kernel_launch(void* const* d_in, const int* in_sizes, int n_in,
                              void* d_out, int out_size, void* d_ws, size_t ws_size,
                              hipStream_t stream)
{
    const float* feat = (const float*)d_in[0];
    const float* W    = (const float*)d_in[1];
    const float* vals = (const float*)d_in[2];
    const int*   erow = (const int*)d_in[3];
    const int*   ecol = (const int*)d_in[4];
    float* out = (float*)d_out;

    const int n_nodes = in_sizes[0] / IN_FEAT;
    const int n_edges = in_sizes[2];
    const int nc = (n_nodes + RBC - 1) / RBC;     // 782 buckets

    char* ws = (char*)d_ws;
    size_t off = 0;
    auto alloc = [&](size_t bytes) { size_t o = off; off = (off + bytes + 15) & ~(size_t)15; return o; };
    unsigned short* x16 = (unsigned short*)(ws + alloc((size_t)n_nodes * OUT_FEAT * sizeof(unsigned short)));
    uint2*    buf1   = (uint2*)(ws + alloc((size_t)nc * CAPC * sizeof(uint2)));
    unsigned* cnt1   = (unsigned*)(ws + alloc((size_t)nc * CNT_STRIDE * sizeof(unsigned)));
    unsigned* ocnt   = (unsigned*)(ws + alloc(sizeof(unsigned)));
    uint4*    obuf   = (uint4*)(ws + alloc((size_t)OCAP * sizeof(uint4)));

    const double lam = (nc > 0) ? (double)n_edges / nc : 0.0;
    const bool sorted_path = (ws_size >= off) && (nc <= NC_MAX) &&
                             (lam + 8.0 * sqrt(lam + 1.0) <= (double)CAPC);

    if (sorted_path) {
        // 1) gemm
        const int tiles = (n_nodes + 15) / 16;
        gemm_mfma_kernel<<<(tiles + 3) / 4, 256, 0, stream>>>(feat, W, x16, n_nodes);

        // zero cnt1 + ocnt (contiguous)
        const int zn = nc * CNT_STRIDE + 4;
        zero_cnt_kernel<<<(zn + 255) / 256, 256, 0, stream>>>(cnt1, zn);

        // 2) partition into 128-row buckets (parallel-scan v2)
        const int nblk = (n_edges + L1_CHUNK - 1) / L1_CHUNK;
        part1_kernel<<<nblk, 512, 0, stream>>>(vals, erow, ecol, buf1, cnt1,
                                               ocnt, obuf, n_edges, nc);

        // 3) fused sort + consume (+ oflow tail blocks)
        sort_consume_kernel<<<nc + OBLK, 512, 0, stream>>>(
            buf1, cnt1, (const unsigned*)x16, out, n_nodes, nc, obuf, ocnt);
    } else {
        float* xf = (float*)d_ws;
        hipMemsetAsync(d_out, 0, (size_t)out_size * sizeof(float), stream);
        long long xtot = (long long)n_nodes * OUT_FEAT;
        gemm_f32_fallback_kernel<<<(unsigned)((xtot + 255) / 256), 256, 0, stream>>>(
            feat, W, xf, n_nodes);
        long long total = (long long)n_edges * OUT_FEAT;
        spmm_scatter_kernel<<<(unsigned)((total + 255) / 256), 256, 0, stream>>>(
            vals, erow, ecol, xf, out, n_edges);
    }
}